// Round 1
// baseline (298.511 us; speedup 1.0000x reference)
//
#include <hip/hip_runtime.h>
#include <math.h>

#define B_G   256
#define IN_D  128
#define FD    256
#define HID   256
#define OUT_D 128
#define TXT   512
#define NT1   128   // nodes per tile, K1
#define NT3   128   // nodes per tile, K3
#define TILES 3     // ceil(383/128)

// ---------------------------------------------------------------------------
// K0: per-graph prep.  q_b = text_emb_b @ Wq + bq ;  qk_b = Wk @ q_b ;
// offsets = exclusive cumsum(lens).  (q.bk is softmax-invariant -> dropped)
// ---------------------------------------------------------------------------
__global__ __launch_bounds__(256) void k_prep(
    const float* __restrict__ text_emb, const float* __restrict__ Wq,
    const float* __restrict__ bq, const float* __restrict__ Wk,
    const int* __restrict__ lens, float* __restrict__ qk,
    int* __restrict__ offsets)
{
    int b = blockIdx.x, t = threadIdx.x;
    __shared__ float te[TXT];
    __shared__ float q[FD];
    for (int i = t; i < TXT; i += 256) te[i] = text_emb[(size_t)b * TXT + i];
    __syncthreads();
    float acc = bq[t];
    for (int k = 0; k < TXT; k++) acc = fmaf(te[k], Wq[k * FD + t], acc);
    q[t] = acc;
    __syncthreads();
    float a2 = 0.f;
    for (int f = 0; f < FD; f++) a2 = fmaf(Wk[t * FD + f], q[f], a2);
    qk[b * FD + t] = a2;
    if (b == 0 && t == 0) {
        int off = 0;
        for (int i = 0; i < B_G; i++) { offsets[i] = off; off += lens[i]; }
        offsets[B_G] = off;
    }
}

// ---------------------------------------------------------------------------
// K1: fused  h = relu(X@W0 + b0)  ->  scores[n] = h_n . qk_b   and
// hsum[b] += sum_n h_n.   h never touches memory.
// block: 256 thr (tx=tid&15, ty=tid>>4); tile 128 nodes x 256 cols; K=128.
// thread tile: 8 nodes x 16 cols.
// ---------------------------------------------------------------------------
__global__ __launch_bounds__(256, 2) void k_layer0(
    const float* __restrict__ X, const float* __restrict__ W0,
    const float* __restrict__ b0, const float* __restrict__ qk,
    const int* __restrict__ offsets,
    float* __restrict__ scores, float* __restrict__ hsum)
{
    int b = blockIdx.y;
    int off = offsets[b];
    int len = offsets[b + 1] - off;
    int n0 = blockIdx.x * NT1;
    if (n0 >= len) return;
    int nvalid = min(NT1, len - n0);
    const float* Xg = X + (size_t)(off + n0) * IN_D;

    __shared__ float Xs[16][NT1 + 4];   // [kk][node]
    __shared__ float Ws[16][FD];        // [kk][col]
    __shared__ float qks[FD];
    __shared__ float bsh[FD];
    __shared__ float red[FD][17];       // [col][ty]

    int tid = threadIdx.x;
    int tx = tid & 15, ty = tid >> 4;

    qks[tid] = qk[b * FD + tid];
    bsh[tid] = b0[tid];

    float acc[8][16];
#pragma unroll
    for (int i = 0; i < 8; i++)
#pragma unroll
        for (int j = 0; j < 16; j++) acc[i][j] = 0.f;

    for (int k0 = 0; k0 < IN_D; k0 += 16) {
        // stage X tile (transposed): 128 nodes x 16 k
#pragma unroll
        for (int r = 0; r < 2; r++) {
            int g = tid + 256 * r;
            int n = g >> 2, kq = (g & 3) * 4;
            float4 xv = make_float4(0.f, 0.f, 0.f, 0.f);
            if (n < nvalid) xv = *(const float4*)(Xg + (size_t)n * IN_D + k0 + kq);
            Xs[kq + 0][n] = xv.x; Xs[kq + 1][n] = xv.y;
            Xs[kq + 2][n] = xv.z; Xs[kq + 3][n] = xv.w;
        }
        // stage W0 tile: 16 k x 256 cols
        {
            const float* wr = W0 + (size_t)(k0 + ty) * FD + tx * 16;
            float4* wd = (float4*)&Ws[ty][tx * 16];
#pragma unroll
            for (int c = 0; c < 4; c++) wd[c] = ((const float4*)wr)[c];
        }
        __syncthreads();
#pragma unroll
        for (int kk = 0; kk < 16; kk++) {
            float a[8];
            float4 a0 = *(float4*)&Xs[kk][ty * 8];
            float4 a1 = *(float4*)&Xs[kk][ty * 8 + 4];
            a[0] = a0.x; a[1] = a0.y; a[2] = a0.z; a[3] = a0.w;
            a[4] = a1.x; a[5] = a1.y; a[6] = a1.z; a[7] = a1.w;
            float w[16];
#pragma unroll
            for (int c = 0; c < 4; c++) {
                float4 wv = *(float4*)&Ws[kk][tx * 4 + 64 * c];
                w[c * 4 + 0] = wv.x; w[c * 4 + 1] = wv.y;
                w[c * 4 + 2] = wv.z; w[c * 4 + 3] = wv.w;
            }
#pragma unroll
            for (int i = 0; i < 8; i++)
#pragma unroll
                for (int j = 0; j < 16; j++)
                    acc[i][j] = fmaf(a[i], w[j], acc[i][j]);
        }
        __syncthreads();
    }

    // epilogue: bias+relu (in regs), score partials, column sums
    float sp[8];
#pragma unroll
    for (int i = 0; i < 8; i++) sp[i] = 0.f;
    float csum[16];
#pragma unroll
    for (int j = 0; j < 16; j++) csum[j] = 0.f;
#pragma unroll
    for (int j = 0; j < 16; j++) {
        int col = 64 * (j >> 2) + tx * 4 + (j & 3);
        float bb = bsh[col];
        float qv = qks[col];
#pragma unroll
        for (int i = 0; i < 8; i++) {
            float h = acc[i][j] + bb;
            h = h > 0.f ? h : 0.f;
            int n = ty * 8 + i;
            h = (n < nvalid) ? h : 0.f;
            sp[i] = fmaf(h, qv, sp[i]);
            csum[j] += h;
        }
    }
    // scores: reduce over tx (lane bits 0..3) via shuffles
#pragma unroll
    for (int i = 0; i < 8; i++) {
        float s = sp[i];
        s += __shfl_xor(s, 1); s += __shfl_xor(s, 2);
        s += __shfl_xor(s, 4); s += __shfl_xor(s, 8);
        sp[i] = s;
    }
    if (tx == 0) {
#pragma unroll
        for (int i = 0; i < 8; i++) {
            int n = ty * 8 + i;
            if (n < nvalid) scores[off + n0 + n] = sp[i];
        }
    }
    // hsum: transpose-reduce over ty via LDS, one atomic per col per block
#pragma unroll
    for (int j = 0; j < 16; j++) {
        int col = 64 * (j >> 2) + tx * 4 + (j & 3);
        red[col][ty] = csum[j];
    }
    __syncthreads();
    {
        float s = 0.f;
#pragma unroll
        for (int r = 0; r < 16; r++) s += red[tid][r];
        atomicAdd(&hsum[b * FD + tid], s);
    }
}

// ---------------------------------------------------------------------------
// K2: per-graph softmax stats + w_b = (hsum_b @ Wv + len*bv) @ Wo
// ---------------------------------------------------------------------------
__global__ __launch_bounds__(256) void k_graph(
    const float* __restrict__ scores, const float* __restrict__ hsum,
    const float* __restrict__ Wv, const float* __restrict__ bv,
    const float* __restrict__ Wo, const int* __restrict__ offsets,
    float* __restrict__ wvec, float* __restrict__ smax, float* __restrict__ dinv)
{
    int b = blockIdx.x, t = threadIdx.x;
    int off = offsets[b], len = offsets[b + 1] - off;
    __shared__ float redm[4];
    __shared__ float reds[4];
    __shared__ float hs[FD];
    __shared__ float vs[FD];

    float m = -INFINITY;
    for (int i = t; i < len; i += 256) m = fmaxf(m, scores[off + i]);
    for (int d = 1; d < 64; d <<= 1) m = fmaxf(m, __shfl_xor(m, d));
    if ((t & 63) == 0) redm[t >> 6] = m;
    __syncthreads();
    m = fmaxf(fmaxf(redm[0], redm[1]), fmaxf(redm[2], redm[3]));

    float s = 0.f;
    for (int i = t; i < len; i += 256) s += expf(scores[off + i] - m);
    for (int d = 1; d < 64; d <<= 1) s += __shfl_xor(s, d);
    if ((t & 63) == 0) reds[t >> 6] = s;
    hs[t] = hsum[b * FD + t];
    __syncthreads();
    s = reds[0] + reds[1] + reds[2] + reds[3];

    float v = bv[t] * (float)len;
    for (int f = 0; f < FD; f++) v = fmaf(hs[f], Wv[f * FD + t], v);
    vs[t] = v;
    __syncthreads();
    float w = 0.f;
    for (int f = 0; f < FD; f++) w = fmaf(vs[f], Wo[f * HID + t], w);
    wvec[b * HID + t] = w;
    if (t == 0) { smax[b] = m; dinv[b] = 1.0f / s; }
}

// ---------------------------------------------------------------------------
// K3: y_n = relu(p_n * w_b + bo) @ W2 + b2.  Left operand generated in-reg.
// block: 256 thr; tile 128 nodes x 128 cols; K=256. thread tile 8x8.
// ---------------------------------------------------------------------------
__global__ __launch_bounds__(256, 2) void k_final(
    const float* __restrict__ scores, const float* __restrict__ wvec,
    const float* __restrict__ bo, const float* __restrict__ W2,
    const float* __restrict__ b2, const float* __restrict__ smax,
    const float* __restrict__ dinv, const int* __restrict__ offsets,
    float* __restrict__ Y)
{
    int b = blockIdx.y;
    int off = offsets[b], len = offsets[b + 1] - off;
    int n0 = blockIdx.x * NT3;
    if (n0 >= len) return;
    int nvalid = min(NT3, len - n0);
    int tid = threadIdx.x, tx = tid & 15, ty = tid >> 4;

    __shared__ float wsh[HID];
    __shared__ float bosh[HID];
    __shared__ float b2sh[OUT_D];
    __shared__ float ps[NT3];
    __shared__ float W2s[16][OUT_D];

    wsh[tid] = wvec[b * HID + tid];
    bosh[tid] = bo[tid];
    if (tid < OUT_D) b2sh[tid] = b2[tid];
    if (tid < NT3) {
        float p = 0.f;
        if (tid < nvalid) p = expf(scores[off + n0 + tid] - smax[b]) * dinv[b];
        ps[tid] = p;
    }
    __syncthreads();

    float p[8];
#pragma unroll
    for (int i = 0; i < 8; i++) p[i] = ps[ty * 8 + i];

    float acc[8][8];
#pragma unroll
    for (int i = 0; i < 8; i++)
#pragma unroll
        for (int j = 0; j < 8; j++) acc[i][j] = 0.f;

    for (int k0 = 0; k0 < HID; k0 += 16) {
        {
            const float* wr = W2 + (size_t)(k0 + ty) * OUT_D + tx * 8;
            float4* wd = (float4*)&W2s[ty][tx * 8];
            wd[0] = ((const float4*)wr)[0];
            wd[1] = ((const float4*)wr)[1];
        }
        __syncthreads();
#pragma unroll
        for (int kk = 0; kk < 16; kk++) {
            float wk = wsh[k0 + kk], bok = bosh[k0 + kk];
            float a[8];
#pragma unroll
            for (int i = 0; i < 8; i++) {
                float z = fmaf(p[i], wk, bok);
                a[i] = z > 0.f ? z : 0.f;
            }
            float wv[8];
            float4 w0v = *(float4*)&W2s[kk][tx * 4];
            float4 w1v = *(float4*)&W2s[kk][64 + tx * 4];
            wv[0] = w0v.x; wv[1] = w0v.y; wv[2] = w0v.z; wv[3] = w0v.w;
            wv[4] = w1v.x; wv[5] = w1v.y; wv[6] = w1v.z; wv[7] = w1v.w;
#pragma unroll
            for (int i = 0; i < 8; i++)
#pragma unroll
                for (int j = 0; j < 8; j++)
                    acc[i][j] = fmaf(a[i], wv[j], acc[i][j]);
        }
        __syncthreads();
    }

    float* Yg = Y + (size_t)(off + n0) * OUT_D;
#pragma unroll
    for (int i = 0; i < 8; i++) {
        int n = ty * 8 + i;
        if (n < nvalid) {
#pragma unroll
            for (int c = 0; c < 2; c++) {
                int col = 64 * c + tx * 4;
                float4 o;
                o.x = acc[i][c * 4 + 0] + b2sh[col + 0];
                o.y = acc[i][c * 4 + 1] + b2sh[col + 1];
                o.z = acc[i][c * 4 + 2] + b2sh[col + 2];
                o.w = acc[i][c * 4 + 3] + b2sh[col + 3];
                *(float4*)(Yg + (size_t)n * OUT_D + col) = o;
            }
        }
    }
}

// ---------------------------------------------------------------------------
extern "C" void kernel_launch(void* const* d_in, const int* in_sizes, int n_in,
                              void* d_out, int out_size, void* d_ws, size_t ws_size,
                              hipStream_t stream)
{
    const float* X        = (const float*)d_in[0];
    const float* text_emb = (const float*)d_in[1];
    const int*   lens     = (const int*)d_in[2];
    const float* W0       = (const float*)d_in[3];
    const float* b0       = (const float*)d_in[4];
    const float* Wq       = (const float*)d_in[5];
    const float* bq       = (const float*)d_in[6];
    const float* Wk       = (const float*)d_in[7];
    // d_in[8] = bk : softmax-invariant, unused
    const float* Wv       = (const float*)d_in[9];
    const float* bv       = (const float*)d_in[10];
    const float* Wo       = (const float*)d_in[11];
    const float* bo       = (const float*)d_in[12];
    const float* W2       = (const float*)d_in[13];
    const float* b2       = (const float*)d_in[14];
    float* Y = (float*)d_out;

    char* base = (char*)d_ws;
    int*   offsets = (int*)base;                               // 257 ints
    float* qk      = (float*)(base + 1088);                    // B*FD
    float* hsum    = (float*)(base + 1088 + 262144);           // B*FD
    float* wvec    = (float*)(base + 1088 + 2 * 262144);       // B*HID
    float* smax    = (float*)(base + 1088 + 3 * 262144);       // B
    float* dinv    = (float*)(base + 1088 + 3 * 262144 + 1024);// B
    float* scores  = (float*)(base + 1088 + 3 * 262144 + 2048);// N

    hipMemsetAsync(hsum, 0, B_G * FD * sizeof(float), stream);
    k_prep<<<B_G, 256, 0, stream>>>(text_emb, Wq, bq, Wk, lens, qk, offsets);
    k_layer0<<<dim3(TILES, B_G), 256, 0, stream>>>(X, W0, b0, qk, offsets, scores, hsum);
    k_graph<<<B_G, 256, 0, stream>>>(scores, hsum, Wv, bv, Wo, offsets, wvec, smax, dinv);
    k_final<<<dim3(TILES, B_G), 256, 0, stream>>>(scores, wvec, bo, W2, b2, smax, dinv, offsets, Y);
}

// Round 2
// 203.751 us; speedup vs baseline: 1.4651x; 1.4651x over previous
//
#include <hip/hip_runtime.h>
#include <math.h>

#define B_G   256
#define IN_D  128
#define FD    256
#define HID   256
#define OUT_D 128
#define TXT   512

typedef short bf16x8 __attribute__((ext_vector_type(8)));   // 8 bf16 (guide-blessed)
typedef float f32x4  __attribute__((ext_vector_type(4)));

#define WPAD 40   // padded k-stride (ushorts): 80 B = 20 banks -> only 2-way conflicts (free)

// ---------------------------------------------------------------------------
// bf16 split helpers (RNE)
// ---------------------------------------------------------------------------
__device__ __forceinline__ unsigned bf_rne(float x) {
    unsigned u = __float_as_uint(x);
    u += 0x7fffu + ((u >> 16) & 1u);
    return u >> 16;
}
__device__ __forceinline__ float bf_to_f(unsigned h) {
    return __uint_as_float(h << 16);
}
// split two floats -> packed hi pair, lo pair (2 bf16 per dword)
__device__ __forceinline__ void split2(float a0, float a1, unsigned& hp, unsigned& lp) {
    unsigned h0 = bf_rne(a0), h1 = bf_rne(a1);
    float r0 = a0 - bf_to_f(h0), r1 = a1 - bf_to_f(h1);
    hp = h0 | (bf_rne(a1) << 16);
    // note: recompute to keep the compiler from aliasing; h1 == bf_rne(a1)
    lp = bf_rne(r0) | (bf_rne(r1) << 16);
    (void)h1;
}

// ---------------------------------------------------------------------------
// K-1: split W0 / W2 into transposed, padded hi/lo bf16 buffers (MFMA B layout)
// W0s[kc=4][col=256][WPAD] : element kk<32 holds W0[(kc*32+kk)*256 + col]
// W2s[kc=8][col=128][WPAD] : element kk<32 holds W2[(kc*32+kk)*128 + col]
// grid: 8 blocks x 256
// ---------------------------------------------------------------------------
__global__ __launch_bounds__(256) void k_wsplit(
    const float* __restrict__ W0, const float* __restrict__ W2,
    unsigned short* __restrict__ W0sH, unsigned short* __restrict__ W0sL,
    unsigned short* __restrict__ W2sH, unsigned short* __restrict__ W2sL)
{
    int t = blockIdx.x * 256 + threadIdx.x;   // 0..2047
    if (t < 1024) {
        int kc = t >> 8, c = t & 255;
        size_t base = (size_t)(kc * 256 + c) * WPAD;
        for (int kk = 0; kk < 32; kk++) {
            float v = W0[(size_t)(kc * 32 + kk) * FD + c];
            unsigned h = bf_rne(v);
            float r = v - bf_to_f(h);
            W0sH[base + kk] = (unsigned short)h;
            W0sL[base + kk] = (unsigned short)bf_rne(r);
        }
    } else {
        int e = t - 1024;                     // 0..1023
        int kc = e >> 7, c = e & 127;
        size_t base = (size_t)(kc * 128 + c) * WPAD;
        for (int kk = 0; kk < 32; kk++) {
            float v = W2[(size_t)(kc * 32 + kk) * OUT_D + c];
            unsigned h = bf_rne(v);
            float r = v - bf_to_f(h);
            W2sH[base + kk] = (unsigned short)h;
            W2sL[base + kk] = (unsigned short)bf_rne(r);
        }
    }
}

// ---------------------------------------------------------------------------
// K0: per-graph prep.  q_b = text_emb_b @ Wq + bq ;  qk_b = Wk @ q_b ;
// offsets = exclusive cumsum(lens).
// ---------------------------------------------------------------------------
__global__ __launch_bounds__(256) void k_prep(
    const float* __restrict__ text_emb, const float* __restrict__ Wq,
    const float* __restrict__ bq, const float* __restrict__ Wk,
    const int* __restrict__ lens, float* __restrict__ qk,
    int* __restrict__ offsets)
{
    int b = blockIdx.x, t = threadIdx.x;
    __shared__ float te[TXT];
    __shared__ float q[FD];
    for (int i = t; i < TXT; i += 256) te[i] = text_emb[(size_t)b * TXT + i];
    __syncthreads();
    float acc = bq[t];
    for (int k = 0; k < TXT; k++) acc = fmaf(te[k], Wq[k * FD + t], acc);
    q[t] = acc;
    __syncthreads();
    float a2 = 0.f;
    for (int f = 0; f < FD; f++) a2 = fmaf(Wk[t * FD + f], q[f], a2);
    qk[b * FD + t] = a2;
    if (b == 0 && t == 0) {
        int off = 0;
        for (int i = 0; i < B_G; i++) { offsets[i] = off; off += lens[i]; }
        offsets[B_G] = off;
    }
}

// ---------------------------------------------------------------------------
// K1: bf16x3 MFMA:  h = relu(X@W0 + b0) -> scores[n] += h.qk (atomic partial),
// hsum[b*FD+c] += col-sums (atomic).  Block: 64 nodes x 256 cols, 4 waves
// (wave w owns cols [64w,64w+64)), K=128 in 4 chunks of 32.
// ---------------------------------------------------------------------------
__global__ __launch_bounds__(256, 2) void k_l0_mfma(
    const float* __restrict__ X,
    const unsigned short* __restrict__ W0sH, const unsigned short* __restrict__ W0sL,
    const float* __restrict__ b0, const float* __restrict__ qk,
    const int* __restrict__ offsets,
    float* __restrict__ scores, float* __restrict__ hsum)
{
    int b = blockIdx.y;
    int off = offsets[b], len = offsets[b + 1] - off;
    int n0 = blockIdx.x * 64;
    if (n0 >= len) return;
    int nvalid = min(64, len - n0);

    __shared__ __align__(16) unsigned short XsH[64 * WPAD], XsL[64 * WPAD];
    __shared__ __align__(16) unsigned short WsH[256 * WPAD], WsL[256 * WPAD];
    __shared__ float qks[FD];
    __shared__ float bsh[FD];

    int tid = threadIdx.x;
    int lane = tid & 63, w = tid >> 6;
    int ln = lane & 15, quad = lane >> 4;

    qks[tid] = qk[b * FD + tid];
    bsh[tid] = b0[tid];

    f32x4 acc[4][4] = {};

    const float* Xg = X + (size_t)(off + n0) * IN_D;
    int node_s = tid >> 2, koff = (tid & 3) * 8;

    for (int kc = 0; kc < 4; kc++) {
        // ---- stage X chunk (fp32 -> bf16 hi/lo) ----
        float xv[8];
        if (node_s < nvalid) {
            const float4* src = (const float4*)(Xg + (size_t)node_s * IN_D + kc * 32 + koff);
            float4 v0 = src[0], v1 = src[1];
            xv[0] = v0.x; xv[1] = v0.y; xv[2] = v0.z; xv[3] = v0.w;
            xv[4] = v1.x; xv[5] = v1.y; xv[6] = v1.z; xv[7] = v1.w;
        } else {
#pragma unroll
            for (int q = 0; q < 8; q++) xv[q] = 0.f;
        }
        uint4 hq, lq;
        split2(xv[0], xv[1], hq.x, lq.x);
        split2(xv[2], xv[3], hq.y, lq.y);
        split2(xv[4], xv[5], hq.z, lq.z);
        split2(xv[6], xv[7], hq.w, lq.w);
        *(uint4*)&XsH[node_s * WPAD + koff] = hq;
        *(uint4*)&XsL[node_s * WPAD + koff] = lq;

        // ---- stage W0 chunk (flat 16B copies; pads carried, never read) ----
        {
            const uint4* gh = (const uint4*)(W0sH + (size_t)kc * 256 * WPAD);
            const uint4* gl = (const uint4*)(W0sL + (size_t)kc * 256 * WPAD);
            uint4* lh = (uint4*)WsH;
            uint4* ll = (uint4*)WsL;
#pragma unroll
            for (int r = 0; r < 5; r++) {
                lh[tid + 256 * r] = gh[tid + 256 * r];
                ll[tid + 256 * r] = gl[tid + 256 * r];
            }
        }
        __syncthreads();

        // ---- fragments + MFMA ----
        bf16x8 AH[4], AL[4], BH[4], BL[4];
#pragma unroll
        for (int i = 0; i < 4; i++) {
            AH[i] = *(const bf16x8*)&XsH[(16 * i + ln) * WPAD + quad * 8];
            AL[i] = *(const bf16x8*)&XsL[(16 * i + ln) * WPAD + quad * 8];
        }
#pragma unroll
        for (int j = 0; j < 4; j++) {
            int c = 64 * w + 16 * j + ln;
            BH[j] = *(const bf16x8*)&WsH[c * WPAD + quad * 8];
            BL[j] = *(const bf16x8*)&WsL[c * WPAD + quad * 8];
        }
#pragma unroll
        for (int i = 0; i < 4; i++)
#pragma unroll
            for (int j = 0; j < 4; j++) {
                acc[i][j] = __builtin_amdgcn_mfma_f32_16x16x32_bf16(AH[i], BH[j], acc[i][j], 0, 0, 0);
                acc[i][j] = __builtin_amdgcn_mfma_f32_16x16x32_bf16(AH[i], BL[j], acc[i][j], 0, 0, 0);
                acc[i][j] = __builtin_amdgcn_mfma_f32_16x16x32_bf16(AL[i], BH[j], acc[i][j], 0, 0, 0);
            }
        __syncthreads();
    }

    // ---- epilogue: bias+relu+mask -> score partials & column sums ----
    float sp[4][4];   // [i][reg] : per-node partial dot over this wave's 64 cols
    float cs[4] = {0.f, 0.f, 0.f, 0.f};   // [j] : per-col sum over 64 nodes
#pragma unroll
    for (int i = 0; i < 4; i++)
#pragma unroll
        for (int r = 0; r < 4; r++) sp[i][r] = 0.f;

#pragma unroll
    for (int i = 0; i < 4; i++)
#pragma unroll
        for (int j = 0; j < 4; j++) {
            int c = 64 * w + 16 * j + ln;
            float bb = bsh[c], qv = qks[c];
#pragma unroll
            for (int r = 0; r < 4; r++) {
                int node = 16 * i + 4 * quad + r;
                float h = acc[i][j][r] + bb;
                h = (h > 0.f && node < nvalid) ? h : 0.f;
                sp[i][r] = fmaf(h, qv, sp[i][r]);
                cs[j] += h;
            }
        }
    // scores: reduce over ln (cols within this wave) via xor-shuffles on bits 0..3
#pragma unroll
    for (int i = 0; i < 4; i++)
#pragma unroll
        for (int r = 0; r < 4; r++) {
            float s = sp[i][r];
            s += __shfl_xor(s, 1); s += __shfl_xor(s, 2);
            s += __shfl_xor(s, 4); s += __shfl_xor(s, 8);
            sp[i][r] = s;
        }
    if (ln == 0) {
#pragma unroll
        for (int i = 0; i < 4; i++)
#pragma unroll
            for (int r = 0; r < 4; r++) {
                int node = 16 * i + 4 * quad + r;
                if (node < nvalid) atomicAdd(&scores[off + n0 + node], sp[i][r]);
            }
    }
    // hsum: reduce over quads (nodes) via xor-shuffles on bits 4..5
#pragma unroll
    for (int j = 0; j < 4; j++) {
        float s = cs[j];
        s += __shfl_xor(s, 16); s += __shfl_xor(s, 32);
        if (quad == 0) atomicAdd(&hsum[b * FD + 64 * w + 16 * j + ln], s);
    }
}

// ---------------------------------------------------------------------------
// K2: per-graph softmax stats + w_b = (hsum_b @ Wv + len*bv) @ Wo
// ---------------------------------------------------------------------------
__global__ __launch_bounds__(256) void k_graph(
    const float* __restrict__ scores, const float* __restrict__ hsum,
    const float* __restrict__ Wv, const float* __restrict__ bv,
    const float* __restrict__ Wo, const int* __restrict__ offsets,
    float* __restrict__ wvec, float* __restrict__ smax, float* __restrict__ dinv)
{
    int b = blockIdx.x, t = threadIdx.x;
    int off = offsets[b], len = offsets[b + 1] - off;
    __shared__ float redm[4];
    __shared__ float reds[4];
    __shared__ float hs[FD];
    __shared__ float vs[FD];

    float m = -INFINITY;
    for (int i = t; i < len; i += 256) m = fmaxf(m, scores[off + i]);
    for (int d = 1; d < 64; d <<= 1) m = fmaxf(m, __shfl_xor(m, d));
    if ((t & 63) == 0) redm[t >> 6] = m;
    __syncthreads();
    m = fmaxf(fmaxf(redm[0], redm[1]), fmaxf(redm[2], redm[3]));

    float s = 0.f;
    for (int i = t; i < len; i += 256) s += expf(scores[off + i] - m);
    for (int d = 1; d < 64; d <<= 1) s += __shfl_xor(s, d);
    if ((t & 63) == 0) reds[t >> 6] = s;
    hs[t] = hsum[b * FD + t];
    __syncthreads();
    s = reds[0] + reds[1] + reds[2] + reds[3];

    float v = bv[t] * (float)len;
    for (int f = 0; f < FD; f++) v = fmaf(hs[f], Wv[f * FD + t], v);
    vs[t] = v;
    __syncthreads();
    float w = 0.f;
    for (int f = 0; f < FD; f++) w = fmaf(vs[f], Wo[f * HID + t], w);
    wvec[b * HID + t] = w;
    if (t == 0) { smax[b] = m; dinv[b] = 1.0f / s; }
}

// ---------------------------------------------------------------------------
// K3: bf16x3 MFMA:  y = relu(p_n * w_b + bo) @ W2 + b2.
// Block: 64 nodes x 128 cols, 4 waves (wave w owns cols [32w,32w+32)),
// K=256 in 8 chunks of 32.  Z generated in LDS from scalars.
// ---------------------------------------------------------------------------
__global__ __launch_bounds__(256, 2) void k_fin_mfma(
    const float* __restrict__ scores, const float* __restrict__ wvec,
    const float* __restrict__ bo,
    const unsigned short* __restrict__ W2sH, const unsigned short* __restrict__ W2sL,
    const float* __restrict__ b2, const float* __restrict__ smax,
    const float* __restrict__ dinv, const int* __restrict__ offsets,
    float* __restrict__ Y)
{
    int b = blockIdx.y;
    int off = offsets[b], len = offsets[b + 1] - off;
    int n0 = blockIdx.x * 64;
    if (n0 >= len) return;
    int nvalid = min(64, len - n0);

    int tid = threadIdx.x;
    int lane = tid & 63, w = tid >> 6;
    int ln = lane & 15, quad = lane >> 4;

    __shared__ __align__(16) unsigned short ZsH[64 * WPAD], ZsL[64 * WPAD];
    __shared__ __align__(16) unsigned short WsH[128 * WPAD], WsL[128 * WPAD];
    __shared__ float ps[64];
    __shared__ float wsh[HID];
    __shared__ float bosh[HID];
    __shared__ float b2sh[OUT_D];

    wsh[tid] = wvec[b * HID + tid];
    bosh[tid] = bo[tid];
    if (tid < OUT_D) b2sh[tid] = b2[tid];
    if (tid < 64) {
        float p = 0.f;
        if (tid < nvalid) p = expf(scores[off + n0 + tid] - smax[b]) * dinv[b];
        ps[tid] = p;
    }
    __syncthreads();

    f32x4 acc[4][2] = {};
    int node_s = tid >> 2, koff = (tid & 3) * 8;
    float pn = ps[node_s];

    for (int kc = 0; kc < 8; kc++) {
        // ---- generate Z chunk: z = relu(p*w + bo), split hi/lo ----
        {
            int kb = kc * 32 + koff;
            uint4 hq, lq;
            float z0, z1;
            z0 = fmaxf(fmaf(pn, wsh[kb + 0], bosh[kb + 0]), 0.f);
            z1 = fmaxf(fmaf(pn, wsh[kb + 1], bosh[kb + 1]), 0.f);
            split2(z0, z1, hq.x, lq.x);
            z0 = fmaxf(fmaf(pn, wsh[kb + 2], bosh[kb + 2]), 0.f);
            z1 = fmaxf(fmaf(pn, wsh[kb + 3], bosh[kb + 3]), 0.f);
            split2(z0, z1, hq.y, lq.y);
            z0 = fmaxf(fmaf(pn, wsh[kb + 4], bosh[kb + 4]), 0.f);
            z1 = fmaxf(fmaf(pn, wsh[kb + 5], bosh[kb + 5]), 0.f);
            split2(z0, z1, hq.z, lq.z);
            z0 = fmaxf(fmaf(pn, wsh[kb + 6], bosh[kb + 6]), 0.f);
            z1 = fmaxf(fmaf(pn, wsh[kb + 7], bosh[kb + 7]), 0.f);
            split2(z0, z1, hq.w, lq.w);
            *(uint4*)&ZsH[node_s * WPAD + koff] = hq;
            *(uint4*)&ZsL[node_s * WPAD + koff] = lq;
        }
        // ---- stage W2 chunk ----
        {
            const uint4* gh = (const uint4*)(W2sH + (size_t)kc * 128 * WPAD);
            const uint4* gl = (const uint4*)(W2sL + (size_t)kc * 128 * WPAD);
            uint4* lh = (uint4*)WsH;
            uint4* ll = (uint4*)WsL;
            lh[tid] = gh[tid];          ll[tid] = gl[tid];
            lh[tid + 256] = gh[tid + 256]; ll[tid + 256] = gl[tid + 256];
            if (tid < 128) { lh[tid + 512] = gh[tid + 512]; ll[tid + 512] = gl[tid + 512]; }
        }
        __syncthreads();

        bf16x8 AH[4], AL[4], BH[2], BL[2];
#pragma unroll
        for (int i = 0; i < 4; i++) {
            AH[i] = *(const bf16x8*)&ZsH[(16 * i + ln) * WPAD + quad * 8];
            AL[i] = *(const bf16x8*)&ZsL[(16 * i + ln) * WPAD + quad * 8];
        }
#pragma unroll
        for (int j = 0; j < 2; j++) {
            int c = 32 * w + 16 * j + ln;
            BH[j] = *(const bf16x8*)&WsH[c * WPAD + quad * 8];
            BL[j] = *(const bf16x8*)&WsL[c * WPAD + quad * 8];
        }
#pragma unroll
        for (int i = 0; i < 4; i++)
#pragma unroll
            for (int j = 0; j < 2; j++) {
                acc[i][j] = __builtin_amdgcn_mfma_f32_16x16x32_bf16(AH[i], BH[j], acc[i][j], 0, 0, 0);
                acc[i][j] = __builtin_amdgcn_mfma_f32_16x16x32_bf16(AH[i], BL[j], acc[i][j], 0, 0, 0);
                acc[i][j] = __builtin_amdgcn_mfma_f32_16x16x32_bf16(AL[i], BH[j], acc[i][j], 0, 0, 0);
            }
        __syncthreads();
    }

    // ---- epilogue: + b2, masked store ----
#pragma unroll
    for (int i = 0; i < 4; i++)
#pragma unroll
        for (int j = 0; j < 2; j++) {
            int c = 32 * w + 16 * j + ln;
            float bb = b2sh[c];
#pragma unroll
            for (int r = 0; r < 4; r++) {
                int node = 16 * i + 4 * quad + r;
                if (node < nvalid)
                    Y[(size_t)(off + n0 + node) * OUT_D + c] = acc[i][j][r] + bb;
            }
        }
}

// ---------------------------------------------------------------------------
extern "C" void kernel_launch(void* const* d_in, const int* in_sizes, int n_in,
                              void* d_out, int out_size, void* d_ws, size_t ws_size,
                              hipStream_t stream)
{
    const float* X        = (const float*)d_in[0];
    const float* text_emb = (const float*)d_in[1];
    const int*   lens     = (const int*)d_in[2];
    const float* W0       = (const float*)d_in[3];
    const float* b0       = (const float*)d_in[4];
    const float* Wq       = (const float*)d_in[5];
    const float* bq       = (const float*)d_in[6];
    const float* Wk       = (const float*)d_in[7];
    // d_in[8] = bk : softmax-invariant, unused
    const float* Wv       = (const float*)d_in[9];
    const float* bv       = (const float*)d_in[10];
    const float* Wo       = (const float*)d_in[11];
    const float* bo       = (const float*)d_in[12];
    const float* W2       = (const float*)d_in[13];
    const float* b2       = (const float*)d_in[14];
    float* Y = (float*)d_out;

    char* base = (char*)d_ws;
    size_t o = 0;
    int*   offsets = (int*)(base + o);            o += 1088;
    float* qkbuf   = (float*)(base + o);          o += 262144;   // B*FD
    float* wvec    = (float*)(base + o);          o += 262144;   // B*HID
    float* smaxb   = (float*)(base + o);          o += 1024;
    float* dinvb   = (float*)(base + o);          o += 1024;
    unsigned short* W0sH = (unsigned short*)(base + o); o += 81920;  // 4*256*40*2
    unsigned short* W0sL = (unsigned short*)(base + o); o += 81920;
    unsigned short* W2sH = (unsigned short*)(base + o); o += 81920;  // 8*128*40*2
    unsigned short* W2sL = (unsigned short*)(base + o); o += 81920;
    float* hsum    = (float*)(base + o);          o += 262144;   // B*FD   (zeroed)
    float* scores  = (float*)(base + o);          o += 262144;   // N      (zeroed)

    // hsum + scores are contiguous -> one memset
    hipMemsetAsync(hsum, 0, 524288, stream);
    k_wsplit<<<8, 256, 0, stream>>>(W0, W2, W0sH, W0sL, W2sH, W2sL);
    k_prep<<<B_G, 256, 0, stream>>>(text_emb, Wq, bq, Wk, lens, qkbuf, offsets);
    k_l0_mfma<<<dim3(6, B_G), 256, 0, stream>>>(X, W0sH, W0sL, b0, qkbuf, offsets, scores, hsum);
    k_graph<<<B_G, 256, 0, stream>>>(scores, hsum, Wv, bv, Wo, offsets, wvec, smaxb, dinvb);
    k_fin_mfma<<<dim3(6, B_G), 256, 0, stream>>>(scores, wvec, bo, W2sH, W2sL, b2, smaxb, dinvb, offsets, Y);
}

// Round 3
// 199.249 us; speedup vs baseline: 1.4982x; 1.0226x over previous
//
#include <hip/hip_runtime.h>
#include <math.h>

#define B_G   256
#define IN_D  128
#define FD    256
#define HID   256
#define OUT_D 128
#define TXT   512
#define XKS   136   // X LDS k-stride (ushorts): 272 B/row, 16B-aligned, <=2-way bank
#define ZKS   264   // Z LDS k-stride (ushorts): 528 B/row, 16B-aligned, <=2-way bank

typedef short bf16x8 __attribute__((ext_vector_type(8)));
typedef float f32x4  __attribute__((ext_vector_type(4)));

// ---------------------------------------------------------------------------
// bf16 split helpers (RNE)
// ---------------------------------------------------------------------------
__device__ __forceinline__ unsigned bf_rne(float x) {
    unsigned u = __float_as_uint(x);
    u += 0x7fffu + ((u >> 16) & 1u);
    return u >> 16;
}
__device__ __forceinline__ float bf_to_f(unsigned h) {
    return __uint_as_float(h << 16);
}
__device__ __forceinline__ void split2(float a0, float a1, unsigned& hp, unsigned& lp) {
    unsigned h0 = bf_rne(a0), h1 = bf_rne(a1);
    float r0 = a0 - bf_to_f(h0), r1 = a1 - bf_to_f(h1);
    hp = h0 | (h1 << 16);
    lp = bf_rne(r0) | (bf_rne(r1) << 16);
}

// ---------------------------------------------------------------------------
// Kernel A (grid 265): fused prep.
//  blocks 0..255  : q_b = te@Wq+bq ; qk_b = Wk@q_b ; zero hsum[b]
//  blocks 256..263: split W0/W2 into tight fragment-layout hi/lo bf16 buffers
//                   W0s[kc=4][col=256][kk=32], W2s[kc=8][col=128][kk=32]
//  block  264     : parallel scan of lens -> offsets (no serial load chain)
// ---------------------------------------------------------------------------
__global__ __launch_bounds__(256) void k_prepA(
    const float* __restrict__ text_emb, const float* __restrict__ Wq,
    const float* __restrict__ bq, const float* __restrict__ Wk,
    const float* __restrict__ W0, const float* __restrict__ W2,
    const int* __restrict__ lens,
    float* __restrict__ qk, int* __restrict__ offsets, float* __restrict__ hsum,
    unsigned short* __restrict__ W0sH, unsigned short* __restrict__ W0sL,
    unsigned short* __restrict__ W2sH, unsigned short* __restrict__ W2sL)
{
    int blk = blockIdx.x, t = threadIdx.x;
    __shared__ float te[TXT];
    __shared__ float q[FD];
    __shared__ int   sc[B_G];

    if (blk < 256) {
        int b = blk;
        hsum[b * FD + t] = 0.f;
        for (int i = t; i < TXT; i += 256) te[i] = text_emb[(size_t)b * TXT + i];
        __syncthreads();
        float acc = bq[t];
        for (int k = 0; k < TXT; k++) acc = fmaf(te[k], Wq[k * FD + t], acc);
        q[t] = acc;
        __syncthreads();
        float a2 = 0.f;
        for (int f = 0; f < FD; f++) a2 = fmaf(Wk[t * FD + f], q[f], a2);
        qk[b * FD + t] = a2;
    } else if (blk < 264) {
        int e = (blk - 256) * 256 + t;   // 0..2047
        if (e < 1024) {
            int kc = e >> 8, c = e & 255;
            size_t base = (size_t)(kc * 256 + c) * 32;
            for (int kk = 0; kk < 32; kk++) {
                float v = W0[(size_t)(kc * 32 + kk) * FD + c];
                unsigned h = bf_rne(v);
                float r = v - bf_to_f(h);
                W0sH[base + kk] = (unsigned short)h;
                W0sL[base + kk] = (unsigned short)bf_rne(r);
            }
        } else {
            int e2 = e - 1024;
            int kc = e2 >> 7, c = e2 & 127;
            size_t base = (size_t)(kc * 128 + c) * 32;
            for (int kk = 0; kk < 32; kk++) {
                float v = W2[(size_t)(kc * 32 + kk) * OUT_D + c];
                unsigned h = bf_rne(v);
                float r = v - bf_to_f(h);
                W2sH[base + kk] = (unsigned short)h;
                W2sL[base + kk] = (unsigned short)bf_rne(r);
            }
        }
    } else {
        // parallel inclusive scan of lens (256 elements, 8 steps)
        sc[t] = lens[t];
        __syncthreads();
        for (int d = 1; d < 256; d <<= 1) {
            int v = (t >= d) ? sc[t - d] : 0;
            __syncthreads();
            sc[t] += v;
            __syncthreads();
        }
        offsets[t + 1] = sc[t];
        if (t == 0) offsets[0] = 0;
    }
}

// ---------------------------------------------------------------------------
// K1: bf16x3 MFMA, barrier-free K-loop.
//  - X tile (64 nodes x K=128) split->LDS ONCE (1 barrier)
//  - W0 B-fragments loaded straight global->VGPR (L2-hot 128 KB, frag-contig)
//  - scores: in-block cross-wave LDS reduce, direct store (no atomics)
//  - hsum: per-col atomic (zeroed by k_prepA)
// ---------------------------------------------------------------------------
__global__ __launch_bounds__(256, 2) void k_l0_mfma(
    const float* __restrict__ X,
    const unsigned short* __restrict__ W0sH, const unsigned short* __restrict__ W0sL,
    const float* __restrict__ b0, const float* __restrict__ qk,
    const int* __restrict__ offsets,
    float* __restrict__ scores, float* __restrict__ hsum)
{
    int b = blockIdx.y;
    int off = offsets[b], len = offsets[b + 1] - off;
    int n0 = blockIdx.x * 64;
    if (n0 >= len) return;
    int nvalid = min(64, len - n0);

    __shared__ __align__(16) unsigned short XsH[64 * XKS], XsL[64 * XKS]; // 2x17408 B
    __shared__ float qks[FD];
    __shared__ float bsh[FD];
    __shared__ float red[4][64];

    int tid = threadIdx.x;
    int lane = tid & 63, w = tid >> 6;
    int ln = lane & 15, quad = lane >> 4;

    qks[tid] = qk[b * FD + tid];
    bsh[tid] = b0[tid];

    // ---- stage X (full K) : thread -> node tid>>2, k-range (tid&3)*32..+32 ----
    {
        int node_s = tid >> 2, ks = (tid & 3) * 32;
        const float* Xr = X + (size_t)(off + n0 + node_s) * IN_D + ks;
        float xv[32];
        if (node_s < nvalid) {
#pragma unroll
            for (int q2 = 0; q2 < 8; q2++) {
                float4 v = ((const float4*)Xr)[q2];
                xv[q2 * 4 + 0] = v.x; xv[q2 * 4 + 1] = v.y;
                xv[q2 * 4 + 2] = v.z; xv[q2 * 4 + 3] = v.w;
            }
        } else {
#pragma unroll
            for (int q2 = 0; q2 < 32; q2++) xv[q2] = 0.f;
        }
#pragma unroll
        for (int g = 0; g < 4; g++) {
            uint4 hq, lq;
            split2(xv[g * 8 + 0], xv[g * 8 + 1], hq.x, lq.x);
            split2(xv[g * 8 + 2], xv[g * 8 + 3], hq.y, lq.y);
            split2(xv[g * 8 + 4], xv[g * 8 + 5], hq.z, lq.z);
            split2(xv[g * 8 + 6], xv[g * 8 + 7], hq.w, lq.w);
            *(uint4*)&XsH[node_s * XKS + ks + g * 8] = hq;
            *(uint4*)&XsL[node_s * XKS + ks + g * 8] = lq;
        }
    }
    __syncthreads();

    f32x4 acc[4][4] = {};
#pragma unroll
    for (int kc = 0; kc < 4; kc++) {
        bf16x8 AH[4], AL[4], BH[4], BL[4];
#pragma unroll
        for (int i = 0; i < 4; i++) {
            AH[i] = *(const bf16x8*)&XsH[(16 * i + ln) * XKS + kc * 32 + quad * 8];
            AL[i] = *(const bf16x8*)&XsL[(16 * i + ln) * XKS + kc * 32 + quad * 8];
        }
#pragma unroll
        for (int j = 0; j < 4; j++) {
            int c = 64 * w + 16 * j + ln;
            size_t base = (size_t)(kc * 256 + c) * 32 + quad * 8;
            BH[j] = *(const bf16x8*)&W0sH[base];
            BL[j] = *(const bf16x8*)&W0sL[base];
        }
#pragma unroll
        for (int i = 0; i < 4; i++)
#pragma unroll
            for (int j = 0; j < 4; j++) {
                acc[i][j] = __builtin_amdgcn_mfma_f32_16x16x32_bf16(AH[i], BH[j], acc[i][j], 0, 0, 0);
                acc[i][j] = __builtin_amdgcn_mfma_f32_16x16x32_bf16(AH[i], BL[j], acc[i][j], 0, 0, 0);
                acc[i][j] = __builtin_amdgcn_mfma_f32_16x16x32_bf16(AL[i], BH[j], acc[i][j], 0, 0, 0);
            }
    }

    // ---- epilogue: bias+relu+mask -> score partials & column sums ----
    float sp[4][4];
    float cs[4] = {0.f, 0.f, 0.f, 0.f};
#pragma unroll
    for (int i = 0; i < 4; i++)
#pragma unroll
        for (int r = 0; r < 4; r++) sp[i][r] = 0.f;

#pragma unroll
    for (int i = 0; i < 4; i++)
#pragma unroll
        for (int j = 0; j < 4; j++) {
            int c = 64 * w + 16 * j + ln;
            float bb = bsh[c], qv = qks[c];
#pragma unroll
            for (int r = 0; r < 4; r++) {
                int node = 16 * i + 4 * quad + r;
                float h = acc[i][j][r] + bb;
                h = (h > 0.f && node < nvalid) ? h : 0.f;
                sp[i][r] = fmaf(h, qv, sp[i][r]);
                cs[j] += h;
            }
        }
    // reduce score partials over ln (16 cols) in-wave
#pragma unroll
    for (int i = 0; i < 4; i++)
#pragma unroll
        for (int r = 0; r < 4; r++) {
            float s = sp[i][r];
            s += __shfl_xor(s, 1); s += __shfl_xor(s, 2);
            s += __shfl_xor(s, 4); s += __shfl_xor(s, 8);
            sp[i][r] = s;
        }
    if (ln == 0) {
#pragma unroll
        for (int i = 0; i < 4; i++)
#pragma unroll
            for (int r = 0; r < 4; r++)
                red[w][16 * i + 4 * quad + r] = sp[i][r];
    }
    // hsum: reduce over quads (nodes), one atomic per col
#pragma unroll
    for (int j = 0; j < 4; j++) {
        float s = cs[j];
        s += __shfl_xor(s, 16); s += __shfl_xor(s, 32);
        if (quad == 0) atomicAdd(&hsum[b * FD + 64 * w + 16 * j + ln], s);
    }
    __syncthreads();
    if (tid < 64 && tid < nvalid)
        scores[off + n0 + tid] = red[0][tid] + red[1][tid] + red[2][tid] + red[3][tid];
}

// ---------------------------------------------------------------------------
// K2: per-graph softmax stats + w_b = (hsum_b @ Wv + len*bv) @ Wo
// 1024 threads: reduction dim split 4x across groups -> short FMA chains.
// ---------------------------------------------------------------------------
__global__ __launch_bounds__(1024) void k_graph(
    const float* __restrict__ scores, const float* __restrict__ hsum,
    const float* __restrict__ Wv, const float* __restrict__ bv,
    const float* __restrict__ Wo, const int* __restrict__ offsets,
    float* __restrict__ wvec, float* __restrict__ smax, float* __restrict__ dinv)
{
    int b = blockIdx.x, tid = threadIdx.x;
    int t = tid & 255, g = tid >> 8;
    int off = offsets[b], len = offsets[b + 1] - off;
    __shared__ float redm[16], reds[16];
    __shared__ float hs[FD], vs[FD];
    __shared__ float part[4][FD];

    float m = -INFINITY;
    for (int i = tid; i < len; i += 1024) m = fmaxf(m, scores[off + i]);
    for (int d = 1; d < 64; d <<= 1) m = fmaxf(m, __shfl_xor(m, d));
    if ((tid & 63) == 0) redm[tid >> 6] = m;
    __syncthreads();
    m = -INFINITY;
#pragma unroll
    for (int k = 0; k < 16; k++) m = fmaxf(m, redm[k]);

    float s = 0.f;
    for (int i = tid; i < len; i += 1024) s += expf(scores[off + i] - m);
    for (int d = 1; d < 64; d <<= 1) s += __shfl_xor(s, d);
    if ((tid & 63) == 0) reds[tid >> 6] = s;
    if (g == 0) hs[t] = hsum[b * FD + t];
    __syncthreads();
    s = 0.f;
#pragma unroll
    for (int k = 0; k < 16; k++) s += reds[k];

    float acc = (g == 0) ? (float)len * bv[t] : 0.f;
    for (int f = 64 * g; f < 64 * g + 64; f++) acc = fmaf(hs[f], Wv[f * FD + t], acc);
    part[g][t] = acc;
    __syncthreads();
    if (g == 0) vs[t] = part[0][t] + part[1][t] + part[2][t] + part[3][t];
    __syncthreads();
    float a2 = 0.f;
    for (int f = 64 * g; f < 64 * g + 64; f++) a2 = fmaf(vs[f], Wo[f * HID + t], a2);
    part[g][t] = a2;
    __syncthreads();
    if (g == 0) wvec[b * HID + t] = part[0][t] + part[1][t] + part[2][t] + part[3][t];
    if (tid == 0) { smax[b] = m; dinv[b] = 1.0f / s; }
}

// ---------------------------------------------------------------------------
// K3: bf16x3 MFMA, barrier-free K-loop.  Z = relu(p*w+bo) generated into
// LDS once for full K=256; W2 B-fragments straight from global.
// ---------------------------------------------------------------------------
__global__ __launch_bounds__(256, 2) void k_fin_mfma(
    const float* __restrict__ scores, const float* __restrict__ wvec,
    const float* __restrict__ bo,
    const unsigned short* __restrict__ W2sH, const unsigned short* __restrict__ W2sL,
    const float* __restrict__ b2, const float* __restrict__ smax,
    const float* __restrict__ dinv, const int* __restrict__ offsets,
    float* __restrict__ Y)
{
    int b = blockIdx.y;
    int off = offsets[b], len = offsets[b + 1] - off;
    int n0 = blockIdx.x * 64;
    if (n0 >= len) return;
    int nvalid = min(64, len - n0);

    int tid = threadIdx.x;
    int lane = tid & 63, w = tid >> 6;
    int ln = lane & 15, quad = lane >> 4;

    __shared__ __align__(16) unsigned short ZsH[64 * ZKS], ZsL[64 * ZKS]; // 2x33792 B
    __shared__ float ps[64];
    __shared__ float wsh[HID];
    __shared__ float bosh[HID];
    __shared__ float b2sh[OUT_D];

    wsh[tid] = wvec[b * HID + tid];
    bosh[tid] = bo[tid];
    if (tid < OUT_D) b2sh[tid] = b2[tid];
    if (tid < 64) {
        float p = 0.f;
        if (tid < nvalid) p = expf(scores[off + n0 + tid] - smax[b]) * dinv[b];
        ps[tid] = p;
    }
    __syncthreads();

    // ---- generate Z (full K=256): thread -> node tid>>2, k-range (tid&3)*64 ----
    {
        int node_s = tid >> 2, ks = (tid & 3) * 64;
        float pn = ps[node_s];
#pragma unroll
        for (int g = 0; g < 8; g++) {
            uint4 hq, lq;
            int kb = ks + g * 8;
            float z0, z1;
            z0 = fmaxf(fmaf(pn, wsh[kb + 0], bosh[kb + 0]), 0.f);
            z1 = fmaxf(fmaf(pn, wsh[kb + 1], bosh[kb + 1]), 0.f);
            split2(z0, z1, hq.x, lq.x);
            z0 = fmaxf(fmaf(pn, wsh[kb + 2], bosh[kb + 2]), 0.f);
            z1 = fmaxf(fmaf(pn, wsh[kb + 3], bosh[kb + 3]), 0.f);
            split2(z0, z1, hq.y, lq.y);
            z0 = fmaxf(fmaf(pn, wsh[kb + 4], bosh[kb + 4]), 0.f);
            z1 = fmaxf(fmaf(pn, wsh[kb + 5], bosh[kb + 5]), 0.f);
            split2(z0, z1, hq.z, lq.z);
            z0 = fmaxf(fmaf(pn, wsh[kb + 6], bosh[kb + 6]), 0.f);
            z1 = fmaxf(fmaf(pn, wsh[kb + 7], bosh[kb + 7]), 0.f);
            split2(z0, z1, hq.w, lq.w);
            *(uint4*)&ZsH[node_s * ZKS + kb] = hq;
            *(uint4*)&ZsL[node_s * ZKS + kb] = lq;
        }
    }
    __syncthreads();

    f32x4 acc[4][2] = {};
#pragma unroll
    for (int kc = 0; kc < 8; kc++) {
        bf16x8 AH[4], AL[4], BH[2], BL[2];
#pragma unroll
        for (int i = 0; i < 4; i++) {
            AH[i] = *(const bf16x8*)&ZsH[(16 * i + ln) * ZKS + kc * 32 + quad * 8];
            AL[i] = *(const bf16x8*)&ZsL[(16 * i + ln) * ZKS + kc * 32 + quad * 8];
        }
#pragma unroll
        for (int j = 0; j < 2; j++) {
            int c = 32 * w + 16 * j + ln;
            size_t base = (size_t)(kc * 128 + c) * 32 + quad * 8;
            BH[j] = *(const bf16x8*)&W2sH[base];
            BL[j] = *(const bf16x8*)&W2sL[base];
        }
#pragma unroll
        for (int i = 0; i < 4; i++)
#pragma unroll
            for (int j = 0; j < 2; j++) {
                acc[i][j] = __builtin_amdgcn_mfma_f32_16x16x32_bf16(AH[i], BH[j], acc[i][j], 0, 0, 0);
                acc[i][j] = __builtin_amdgcn_mfma_f32_16x16x32_bf16(AH[i], BL[j], acc[i][j], 0, 0, 0);
                acc[i][j] = __builtin_amdgcn_mfma_f32_16x16x32_bf16(AL[i], BH[j], acc[i][j], 0, 0, 0);
            }
    }

    // ---- epilogue: + b2, masked store ----
#pragma unroll
    for (int i = 0; i < 4; i++)
#pragma unroll
        for (int j = 0; j < 2; j++) {
            int c = 32 * w + 16 * j + ln;
            float bb = b2sh[c];
#pragma unroll
            for (int r = 0; r < 4; r++) {
                int node = 16 * i + 4 * quad + r;
                if (node < nvalid)
                    Y[(size_t)(off + n0 + node) * OUT_D + c] = acc[i][j][r] + bb;
            }
        }
}

// ---------------------------------------------------------------------------
extern "C" void kernel_launch(void* const* d_in, const int* in_sizes, int n_in,
                              void* d_out, int out_size, void* d_ws, size_t ws_size,
                              hipStream_t stream)
{
    const float* X        = (const float*)d_in[0];
    const float* text_emb = (const float*)d_in[1];
    const int*   lens     = (const int*)d_in[2];
    const float* W0       = (const float*)d_in[3];
    const float* b0       = (const float*)d_in[4];
    const float* Wq       = (const float*)d_in[5];
    const float* bq       = (const float*)d_in[6];
    const float* Wk       = (const float*)d_in[7];
    // d_in[8] = bk : softmax-invariant, unused
    const float* Wv       = (const float*)d_in[9];
    const float* bv       = (const float*)d_in[10];
    const float* Wo       = (const float*)d_in[11];
    const float* bo       = (const float*)d_in[12];
    const float* W2       = (const float*)d_in[13];
    const float* b2       = (const float*)d_in[14];
    float* Y = (float*)d_out;

    char* base = (char*)d_ws;
    size_t o = 0;
    int*   offsets = (int*)(base + o);            o += 1088;
    float* qkbuf   = (float*)(base + o);          o += 262144;
    float* wvec    = (float*)(base + o);          o += 262144;
    float* smaxb   = (float*)(base + o);          o += 1024;
    float* dinvb   = (float*)(base + o);          o += 1024;
    float* hsum    = (float*)(base + o);          o += 262144;
    float* scores  = (float*)(base + o);          o += 262144;
    unsigned short* W0sH = (unsigned short*)(base + o); o += 65536;
    unsigned short* W0sL = (unsigned short*)(base + o); o += 65536;
    unsigned short* W2sH = (unsigned short*)(base + o); o += 65536;
    unsigned short* W2sL = (unsigned short*)(base + o); o += 65536;

    k_prepA<<<265, 256, 0, stream>>>(text_emb, Wq, bq, Wk, W0, W2, lens,
                                     qkbuf, offsets, hsum, W0sH, W0sL, W2sH, W2sL);
    k_l0_mfma<<<dim3(6, B_G), 256, 0, stream>>>(X, W0sH, W0sL, b0, qkbuf, offsets, scores, hsum);
    k_graph<<<B_G, 1024, 0, stream>>>(scores, hsum, Wv, bv, Wo, offsets, wvec, smaxb, dinvb);
    k_fin_mfma<<<dim3(6, B_G), 256, 0, stream>>>(scores, wvec, bo, W2sH, W2sL, b2, smaxb, dinvb, offsets, Y);
}